// Round 1
// baseline (796.750 us; speedup 1.0000x reference)
//
#include <hip/hip_runtime.h>
#include <math.h>

// Sizes
#define DIM 512
#define NS 3
#define NB 256
#define NHEAD 8
#define HDIM 64
#define NPOW 4
#define NGROUP 8
#define KMAX (NPOW*NGROUP)  // 32 Taylor terms

// ---------------------------------------------------------------------------
// Generic fp32 GEMM:  C[m,n] = sum_k X[m,k] * B[n,k]  (+ bias[n]) (+= if acc)
// Tiles 32x32, 256 threads, 2x2 per thread. M,N,K all multiples of 32.
// ---------------------------------------------------------------------------
__global__ __launch_bounds__(256) void gemm_bt(
    const float* __restrict__ X, const float* __restrict__ B,
    const float* __restrict__ bias, float* __restrict__ C,
    int M, int N, int K, int accumulate)
{
    __shared__ float sX[32][33];
    __shared__ float sB[32][33];
    int tid = threadIdx.x;
    int tx = tid & 15, ty = tid >> 4;
    int n0 = blockIdx.x * 32, m0 = blockIdx.y * 32;

    float a00 = 0.f, a01 = 0.f, a10 = 0.f, a11 = 0.f;

    for (int kt = 0; kt < K; kt += 32) {
        #pragma unroll
        for (int i = 0; i < 4; ++i) {
            int l = tid + i * 256;
            int r = l >> 5, c = l & 31;
            sX[r][c] = X[(size_t)(m0 + r) * K + kt + c];
            sB[r][c] = B[(size_t)(n0 + r) * K + kt + c];
        }
        __syncthreads();
        #pragma unroll
        for (int k = 0; k < 32; ++k) {
            float x0 = sX[ty][k],      x1 = sX[ty + 16][k];
            float b0 = sB[tx][k],      b1 = sB[tx + 16][k];
            a00 += x0 * b0; a01 += x0 * b1;
            a10 += x1 * b0; a11 += x1 * b1;
        }
        __syncthreads();
    }

    int m = m0 + ty, n = n0 + tx;
    float bv0 = bias ? bias[n] : 0.f;
    float bv1 = bias ? bias[n + 16] : 0.f;
    size_t i00 = (size_t)m * N + n;
    size_t i10 = (size_t)(m + 16) * N + n;
    if (accumulate) {
        C[i00]       += a00 + bv0;
        C[i00 + 16]  += a01 + bv1;
        C[i10]       += a10 + bv0;
        C[i10 + 16]  += a11 + bv1;
    } else {
        C[i00]       = a00 + bv0;
        C[i00 + 16]  = a01 + bv1;
        C[i10]       = a10 + bv0;
        C[i10 + 16]  = a11 + bv1;
    }
}

// ---------------------------------------------------------------------------
// 512x512 transpose
// ---------------------------------------------------------------------------
__global__ void transpose512(const float* __restrict__ in, float* __restrict__ out)
{
    __shared__ float tile[32][33];
    int x = blockIdx.x * 32 + threadIdx.x;
    int y = blockIdx.y * 32 + threadIdx.y;
    #pragma unroll
    for (int i = 0; i < 32; i += 8)
        tile[threadIdx.y + i][threadIdx.x] = in[(size_t)(y + i) * DIM + x];
    __syncthreads();
    x = blockIdx.y * 32 + threadIdx.x;
    y = blockIdx.x * 32 + threadIdx.y;
    #pragma unroll
    for (int i = 0; i < 32; i += 8)
        out[(size_t)(y + i) * DIM + x] = tile[threadIdx.x][threadIdx.y + i];
}

// ---------------------------------------------------------------------------
// block reduce (256 threads = 4 waves) of two values
// ---------------------------------------------------------------------------
__device__ __forceinline__ void block_reduce2(float& s, float& q,
                                              float* sb1, float* sb2)
{
    int tid = threadIdx.x;
    #pragma unroll
    for (int off = 32; off > 0; off >>= 1) {
        s += __shfl_down(s, off);
        q += __shfl_down(q, off);
    }
    if ((tid & 63) == 0) { sb1[tid >> 6] = s; sb2[tid >> 6] = q; }
    __syncthreads();
    s = sb1[0] + sb1[1] + sb1[2] + sb1[3];
    q = sb2[0] + sb2[1] + sb2[2] + sb2[3];
    __syncthreads();
}

// ---------------------------------------------------------------------------
// LayerNorm + GELU(exact) + delta = softplus(h1 . w2 + b2).  One block/row.
// ---------------------------------------------------------------------------
__global__ __launch_bounds__(256) void ln_gelu_delta(
    const float* __restrict__ pre, const float* __restrict__ g,
    const float* __restrict__ beta, const float* __restrict__ w2,
    const float* __restrict__ b2, float* __restrict__ h1out,
    float* __restrict__ delta)
{
    __shared__ float sb1[4], sb2[4];
    int b = blockIdx.x, tid = threadIdx.x;
    int i0 = tid, i1 = tid + 256;
    float x0 = pre[(size_t)b * DIM + i0];
    float x1 = pre[(size_t)b * DIM + i1];
    float s = x0 + x1, q = x0 * x0 + x1 * x1;
    block_reduce2(s, q, sb1, sb2);
    float mean = s * (1.f / DIM);
    float var  = q * (1.f / DIM) - mean * mean;
    float inv  = rsqrtf(var + 1e-5f);
    float y0 = (x0 - mean) * inv * g[i0] + beta[i0];
    float y1 = (x1 - mean) * inv * g[i1] + beta[i1];
    float h0 = 0.5f * y0 * (1.f + erff(y0 * 0.70710678118654752f));
    float h1 = 0.5f * y1 * (1.f + erff(y1 * 0.70710678118654752f));
    h1out[(size_t)b * DIM + i0] = h0;
    h1out[(size_t)b * DIM + i1] = h1;
    float p = h0 * w2[i0] + h1 * w2[i1];
    float dummy = 0.f;
    block_reduce2(p, dummy, sb1, sb2);
    if (tid == 0) {
        float z = p + b2[0];
        delta[b] = (z > 20.f) ? z : log1pf(expf(z));
    }
}

// ---------------------------------------------------------------------------
// Plain LayerNorm (final).  One block/row.
// ---------------------------------------------------------------------------
__global__ __launch_bounds__(256) void layernorm_k(
    const float* __restrict__ in, const float* __restrict__ g,
    const float* __restrict__ beta, float* __restrict__ outp)
{
    __shared__ float sb1[4], sb2[4];
    int b = blockIdx.x, tid = threadIdx.x;
    int i0 = tid, i1 = tid + 256;
    float x0 = in[(size_t)b * DIM + i0];
    float x1 = in[(size_t)b * DIM + i1];
    float s = x0 + x1, q = x0 * x0 + x1 * x1;
    block_reduce2(s, q, sb1, sb2);
    float mean = s * (1.f / DIM);
    float var  = q * (1.f / DIM) - mean * mean;
    float inv  = rsqrtf(var + 1e-5f);
    outp[(size_t)b * DIM + i0] = (x0 - mean) * inv * g[i0] + beta[i0];
    outp[(size_t)b * DIM + i1] = (x1 - mean) * inv * g[i1] + beta[i1];
}

// ---------------------------------------------------------------------------
// Taylor coefficients: coeff[k*256+b] = delta_b^k / k!
// ---------------------------------------------------------------------------
__global__ void coeff_kernel(const float* __restrict__ delta, float* __restrict__ coeff)
{
    int b = threadIdx.x;
    float d = delta[b], c = 1.f;
    coeff[b] = 1.f;
    for (int k = 1; k <= KMAX; ++k) { c *= d / (float)k; coeff[k * 256 + b] = c; }
}

// ---------------------------------------------------------------------------
// Taylor accumulate: acc += sum_{p=1..4} coeff[4g+p][b] * T[b, (p-1)*512 + i]
// U <- T[:, 3*512:],   final: h_ssm = acc + delta[b]*Bx
// ---------------------------------------------------------------------------
__global__ void taylor_accum(
    const float* __restrict__ T, const float* __restrict__ coeff, int g,
    const float* __restrict__ accIn, float* __restrict__ accOut,
    float* __restrict__ U, int final_flag,
    const float* __restrict__ delta, const float* __restrict__ Bx,
    float* __restrict__ hssm)
{
    int idx = blockIdx.x * 256 + threadIdx.x;   // 0..131071
    int b = idx >> 9, i = idx & 511;
    const float* Tr = T + (size_t)b * (4 * DIM);
    int k0 = g * 4;
    float a = accIn[idx]
            + coeff[(k0 + 1) * 256 + b] * Tr[i]
            + coeff[(k0 + 2) * 256 + b] * Tr[DIM + i]
            + coeff[(k0 + 3) * 256 + b] * Tr[2 * DIM + i]
            + coeff[(k0 + 4) * 256 + b] * Tr[3 * DIM + i];
    U[idx] = Tr[3 * DIM + i];
    if (final_flag) hssm[idx] = a + delta[b] * Bx[idx];
    else            accOut[idx] = a;
}

// ---------------------------------------------------------------------------
// LSTM cell elementwise.  idx over (s, b, d) = 3*256*512
// ---------------------------------------------------------------------------
__global__ void lstm_cell(
    const float* __restrict__ gates, const float* __restrict__ bih,
    const float* __restrict__ bhh, const float* __restrict__ cin,
    const float* __restrict__ decays,
    float* __restrict__ hout, float* __restrict__ cout)
{
    int idx = blockIdx.x * 256 + threadIdx.x;   // 0..393215
    int s = idx / (NB * DIM);
    int r = idx - s * (NB * DIM);
    int b = r >> 9, d = r & 511;
    const float* gr = gates + (size_t)s * NB * 4 * DIM + (size_t)b * 4 * DIM;
    const float* bi = bih + s * 4 * DIM;
    const float* bh = bhh + s * 4 * DIM;
    float gi = gr[d]            + bi[d]            + bh[d];
    float gf = gr[DIM + d]      + bi[DIM + d]      + bh[DIM + d];
    float gg = gr[2 * DIM + d]  + bi[2 * DIM + d]  + bh[2 * DIM + d];
    float go = gr[3 * DIM + d]  + bi[3 * DIM + d]  + bh[3 * DIM + d];
    float ig = 1.f / (1.f + expf(-gi));
    float fg = 1.f / (1.f + expf(-gf));
    float g_ = tanhf(gg);
    float og = 1.f / (1.f + expf(-go));
    float c  = cin[idx];
    float craw = fg * c + ig * g_;
    float hn = og * tanhf(craw);
    float dec = decays[s];
    hout[idx] = hn;
    cout[idx] = dec * c + (1.f - dec) * craw;
}

// ---------------------------------------------------------------------------
// Attention: q len 1, kv len 3 per (b,h).  One wave per (b,h).
// kbuf/vbuf rows indexed (s*256+b).
// ---------------------------------------------------------------------------
__global__ __launch_bounds__(64) void attn_kernel(
    const float* __restrict__ q, const float* __restrict__ kbuf,
    const float* __restrict__ vbuf, float* __restrict__ ctx)
{
    int bh = blockIdx.x;
    int b = bh >> 3, h = bh & 7;
    int e = threadIdx.x;
    int col = h * HDIM + e;
    float qe = q[(size_t)b * DIM + col];
    float p0 = qe * kbuf[(size_t)(0 * NB + b) * DIM + col];
    float p1 = qe * kbuf[(size_t)(1 * NB + b) * DIM + col];
    float p2 = qe * kbuf[(size_t)(2 * NB + b) * DIM + col];
    #pragma unroll
    for (int off = 32; off > 0; off >>= 1) {
        p0 += __shfl_xor(p0, off);
        p1 += __shfl_xor(p1, off);
        p2 += __shfl_xor(p2, off);
    }
    const float scale = 0.125f;   // 1/sqrt(64)
    p0 *= scale; p1 *= scale; p2 *= scale;
    float m = fmaxf(p0, fmaxf(p1, p2));
    float w0 = expf(p0 - m), w1 = expf(p1 - m), w2 = expf(p2 - m);
    float invs = 1.f / (w0 + w1 + w2);
    float v0 = vbuf[(size_t)(0 * NB + b) * DIM + col];
    float v1 = vbuf[(size_t)(1 * NB + b) * DIM + col];
    float v2 = vbuf[(size_t)(2 * NB + b) * DIM + col];
    ctx[(size_t)b * DIM + col] = (w0 * v0 + w1 * v1 + w2 * v2) * invs;
}

// ---------------------------------------------------------------------------
// combined = [h_ssm | fused | h_new0 | h_new1 | h_new2]   (256 x 2560)
// ---------------------------------------------------------------------------
__global__ void assemble_combined(
    const float* __restrict__ hssm, const float* __restrict__ fused,
    const float* __restrict__ hnew, float* __restrict__ comb)
{
    int idx = blockIdx.x * 256 + threadIdx.x;   // 0..655359
    int b = idx / 2560, c = idx - b * 2560;
    float v;
    if (c < DIM)            v = hssm[(size_t)b * DIM + c];
    else if (c < 2 * DIM)   v = fused[(size_t)b * DIM + (c - DIM)];
    else {
        int s = (c - 2 * DIM) >> 9;
        int d = (c - 2 * DIM) & 511;
        v = hnew[(size_t)s * NB * DIM + (size_t)b * DIM + d];
    }
    comb[idx] = v;
}

// ---------------------------------------------------------------------------
extern "C" void kernel_launch(void* const* d_in, const int* in_sizes, int n_in,
                              void* d_out, int out_size, void* d_ws, size_t ws_size,
                              hipStream_t stream)
{
    const float* x        = (const float*)d_in[0];
    const float* h_prev   = (const float*)d_in[1];
    const float* lstm_h   = (const float*)d_in[2];
    const float* lstm_c   = (const float*)d_in[3];
    const float* A        = (const float*)d_in[4];
    const float* Bm       = (const float*)d_in[5];
    const float* dn_w1    = (const float*)d_in[6];
    const float* dn_b1    = (const float*)d_in[7];
    const float* dn_g     = (const float*)d_in[8];
    const float* dn_beta  = (const float*)d_in[9];
    const float* dn_w2    = (const float*)d_in[10];
    const float* dn_b2    = (const float*)d_in[11];
    const float* wih      = (const float*)d_in[12];
    const float* whh      = (const float*)d_in[13];
    const float* bih      = (const float*)d_in[14];
    const float* bhh      = (const float*)d_in[15];
    const float* decays   = (const float*)d_in[16];
    const float* ain_w    = (const float*)d_in[17];
    const float* ain_b    = (const float*)d_in[18];
    const float* aout_w   = (const float*)d_in[19];
    const float* aout_b   = (const float*)d_in[20];
    const float* proj_w   = (const float*)d_in[21];
    const float* proj_b   = (const float*)d_in[22];
    const float* proj_g   = (const float*)d_in[23];
    const float* proj_bt  = (const float*)d_in[24];

    float* out  = (float*)d_out;         // (256,512)
    float* hssm = out + 131072;          // (256,512)
    float* hnew = out + 262144;          // (3,256,512)
    float* cnew = out + 655360;          // (3,256,512)

    float* ws     = (float*)d_ws;
    float* pre1   = ws;                  // 131072 (reused as projout)
    float* h1     = ws + 131072;         // 131072
    float* delta  = ws + 262144;         // 256
    float* coeff  = ws + 262400;         // 33*256 = 8448
    float* Bx     = ws + 270848;         // 131072
    float* AT     = ws + 401920;         // 262144
    float* Pw     = ws + 664064;         // 4*262144 = 1048576  [A|A2|A3|A4]
    float* Tm     = ws + 1712640;        // 256*2048 = 524288
    float* gates  = Pw;                  // alias: 3*256*2048 = 1572864 = Pw+Tm
    float* U      = ws + 2236928;        // 131072
    float* acc    = ws + 2368000;        // 131072
    float* qb     = ws + 2499072;        // 131072
    float* kb     = ws + 2630144;        // 393216
    float* vb     = ws + 3023360;        // 393216
    float* ctx    = ws + 3416576;        // 131072
    float* fusedb = ws + 3547648;        // 131072
    float* comb   = ws + 3678720;        // 655360   (end: 4334080 floats)
    float* projout= pre1;

    dim3 blk(256);

    // Stage 1: dense1 -> LN -> GELU -> delta
    gemm_bt<<<dim3(16, 8), blk, 0, stream>>>(x, dn_w1, dn_b1, pre1, 256, 512, 512, 0);
    ln_gelu_delta<<<256, 256, 0, stream>>>(pre1, dn_g, dn_beta, dn_w2, dn_b2, h1, delta);
    coeff_kernel<<<1, 256, 0, stream>>>(delta, coeff);

    // Stage 2: Bx = x @ Bm^T ; powers of A
    gemm_bt<<<dim3(16, 8), blk, 0, stream>>>(x, Bm, nullptr, Bx, 256, 512, 512, 0);
    transpose512<<<dim3(16, 16), dim3(32, 8), 0, stream>>>(A, AT);
    hipMemcpyAsync(Pw, A, (size_t)512 * 512 * sizeof(float),
                   hipMemcpyDeviceToDevice, stream);
    gemm_bt<<<dim3(16, 16), blk, 0, stream>>>(A,            AT, nullptr, Pw + 262144, 512, 512, 512, 0); // A^2
    gemm_bt<<<dim3(16, 16), blk, 0, stream>>>(Pw + 262144,  AT, nullptr, Pw + 524288, 512, 512, 512, 0); // A^3
    gemm_bt<<<dim3(16, 16), blk, 0, stream>>>(Pw + 524288,  AT, nullptr, Pw + 786432, 512, 512, 512, 0); // A^4

    // Stage 3: Taylor series, 8 groups x 4 powers = 32 terms
    for (int g = 0; g < NGROUP; ++g) {
        const float* Xp = (g == 0) ? h_prev : U;
        gemm_bt<<<dim3(64, 8), blk, 0, stream>>>(Xp, Pw, nullptr, Tm, 256, 2048, 512, 0);
        taylor_accum<<<512, 256, 0, stream>>>(Tm, coeff, g,
            (g == 0) ? h_prev : acc, acc, U, (g == NGROUP - 1) ? 1 : 0,
            delta, Bx, hssm);
    }

    // Stage 4: LSTM gates + cell   (gates aliases Pw/Tm — Taylor is done)
    for (int s = 0; s < 3; ++s) {
        gemm_bt<<<dim3(64, 8), blk, 0, stream>>>(
            x, wih + (size_t)s * 1048576, nullptr, gates + (size_t)s * 524288,
            256, 2048, 512, 0);
        gemm_bt<<<dim3(64, 8), blk, 0, stream>>>(
            lstm_h + (size_t)s * 131072, whh + (size_t)s * 1048576, nullptr,
            gates + (size_t)s * 524288, 256, 2048, 512, 1);
    }
    lstm_cell<<<1536, 256, 0, stream>>>(gates, bih, bhh, lstm_c, decays, hnew, cnew);

    // Stage 5: attention
    gemm_bt<<<dim3(16, 8),  blk, 0, stream>>>(hssm, ain_w,           ain_b,        qb, 256, 512, 512, 0);
    gemm_bt<<<dim3(16, 24), blk, 0, stream>>>(hnew, ain_w + 262144,  ain_b + 512,  kb, 768, 512, 512, 0);
    gemm_bt<<<dim3(16, 24), blk, 0, stream>>>(hnew, ain_w + 524288,  ain_b + 1024, vb, 768, 512, 512, 0);
    attn_kernel<<<2048, 64, 0, stream>>>(qb, kb, vb, ctx);
    gemm_bt<<<dim3(16, 8), blk, 0, stream>>>(ctx, aout_w, aout_b, fusedb, 256, 512, 512, 0);

    // Stage 6: combined -> proj -> LN
    assemble_combined<<<2560, 256, 0, stream>>>(hssm, fusedb, hnew, comb);
    gemm_bt<<<dim3(16, 8), blk, 0, stream>>>(comb, proj_w, proj_b, projout, 256, 512, 2560, 0);
    layernorm_k<<<256, 256, 0, stream>>>(projout, proj_g, proj_bt, out);
}

// Round 3
// 351.108 us; speedup vs baseline: 2.2692x; 2.2692x over previous
//
#include <hip/hip_runtime.h>
#include <math.h>

#define DIM 512
#define NS 3
#define NB 256
#define NGROUP 6
#define KMAX (4*NGROUP)   // 24 Taylor terms

using bf16x8 = __attribute__((ext_vector_type(8))) short;
using f32x4  = __attribute__((ext_vector_type(4))) float;
using float4v = __attribute__((ext_vector_type(4))) float;

// fp32 -> bf16 (RNE) and back
__device__ __forceinline__ unsigned short f2b(float f) {
    union { float f; unsigned int u; } v; v.f = f;
    unsigned int r = v.u + 0x7fffu + ((v.u >> 16) & 1u);
    return (unsigned short)(r >> 16);
}
__device__ __forceinline__ float b2f(unsigned short u) {
    union { unsigned int u; float f; } v; v.u = ((unsigned int)u) << 16;
    return v.f;
}

// ---------------------------------------------------------------------------
// Batched bf16 MFMA GEMM:  C[m,n] = sum_k X[m,k]*W[n,k] + bias[n]
// X: (M,K) bf16 ld=ldX.  W: (N,K) bf16 ld=K.  C: fp32 (Cf) or bf16 (Cb), ld=ldC.
// Tile 64x64, BK=32, 256 threads (4 waves 2x2), double-buffered LDS,
// global_load_lds dwordx4 staging, k-major LDS layout (conflict-free b128).
// M,N multiples of 64; K multiple of 32.
// ---------------------------------------------------------------------------
struct GemmDesc {
    const unsigned short* X;
    const unsigned short* W;
    const float* bias;
    float* Cf;
    unsigned short* Cb;
    int M, N, K, ldX, ldC;
};
struct GemmArgs { GemmDesc d[4]; };

__global__ __launch_bounds__(256) void gemm_mfma(GemmArgs args)
{
    GemmDesc de = args.d[blockIdx.y];
    int tn = de.N >> 6;
    int tiles = (de.M >> 6) * tn;
    int t = blockIdx.x;
    if (t >= tiles) return;
    int m0 = (t / tn) << 6;
    int n0 = (t % tn) << 6;

    // LDS: [buf][kg(0..3)*64 + row] * 8 bf16   (16B slots, lane-linear staging)
    __shared__ unsigned short lsA[2][2048];
    __shared__ unsigned short lsB[2][2048];

    int tid = threadIdx.x;
    int w = tid >> 6;        // wave 0..3
    int l = tid & 63;        // lane

    int nkt = de.K >> 5;

    // staging addresses: wave w loads k-group w, row = lane
    const unsigned short* gA = de.X + (size_t)(m0 + l) * de.ldX + w * 8;
    const unsigned short* gB = de.W + (size_t)(n0 + l) * de.K  + w * 8;
    unsigned short* lA = &lsA[0][(w * 64 + l) * 8];
    unsigned short* lB = &lsB[0][(w * 64 + l) * 8];

#define STAGE(bufi, kt)                                                          \
    do {                                                                         \
        __builtin_amdgcn_global_load_lds(                                        \
            (const __attribute__((address_space(1))) unsigned int*)(gA + (size_t)(kt) * 32), \
            (__attribute__((address_space(3))) unsigned int*)(lA + (bufi) * 2048), 16, 0, 0); \
        __builtin_amdgcn_global_load_lds(                                        \
            (const __attribute__((address_space(1))) unsigned int*)(gB + (size_t)(kt) * 32), \
            (__attribute__((address_space(3))) unsigned int*)(lB + (bufi) * 2048), 16, 0, 0); \
    } while (0)

    int mbase = (w >> 1) * 32;   // wave's 32x32 subtile
    int nbase = (w & 1) * 32;

    f32x4 acc[2][2];
    #pragma unroll
    for (int i = 0; i < 2; ++i)
        #pragma unroll
        for (int j = 0; j < 2; ++j)
            acc[i][j] = (f32x4){0.f, 0.f, 0.f, 0.f};

    int kg = l >> 4;       // 0..3
    int fr = l & 15;       // frag row/col

    STAGE(0, 0);

    for (int kt = 0; kt < nkt; ++kt) {
        __syncthreads();                    // drains vmcnt -> buf[kt&1] ready
        if (kt + 1 < nkt) STAGE((kt + 1) & 1, kt + 1);

        const unsigned short* bufA = &lsA[kt & 1][0];
        const unsigned short* bufB = &lsB[kt & 1][0];
        // frag addr: slot = kg*64 + (base + f*16 + fr)
        bf16x8 a0 = *(const bf16x8*)(bufA + (kg * 64 + mbase + fr) * 8);
        bf16x8 a1 = *(const bf16x8*)(bufA + (kg * 64 + mbase + 16 + fr) * 8);
        bf16x8 b0 = *(const bf16x8*)(bufB + (kg * 64 + nbase + fr) * 8);
        bf16x8 b1 = *(const bf16x8*)(bufB + (kg * 64 + nbase + 16 + fr) * 8);

        acc[0][0] = __builtin_amdgcn_mfma_f32_16x16x32_bf16(a0, b0, acc[0][0], 0, 0, 0);
        acc[0][1] = __builtin_amdgcn_mfma_f32_16x16x32_bf16(a0, b1, acc[0][1], 0, 0, 0);
        acc[1][0] = __builtin_amdgcn_mfma_f32_16x16x32_bf16(a1, b0, acc[1][0], 0, 0, 0);
        acc[1][1] = __builtin_amdgcn_mfma_f32_16x16x32_bf16(a1, b1, acc[1][1], 0, 0, 0);
    }

    // epilogue: C/D layout col = lane&15, row = (lane>>4)*4 + reg
    #pragma unroll
    for (int mi = 0; mi < 2; ++mi) {
        #pragma unroll
        for (int ni = 0; ni < 2; ++ni) {
            int col = n0 + nbase + ni * 16 + fr;
            float bv = de.bias ? de.bias[col] : 0.f;
            #pragma unroll
            for (int r = 0; r < 4; ++r) {
                int row = m0 + mbase + mi * 16 + (l >> 4) * 4 + r;
                float v = acc[mi][ni][r] + bv;
                if (de.Cf) de.Cf[(size_t)row * de.ldC + col] = v;
                else       de.Cb[(size_t)row * de.ldC + col] = f2b(v);
            }
        }
    }
#undef STAGE
}

// ---------------------------------------------------------------------------
// multi-array fp32 -> bf16 convert (vectorized by 4)
// ---------------------------------------------------------------------------
struct ConvArgs { const float* s[8]; unsigned short* d[8]; int n4[8]; int nseg; };
__global__ void convert_pairs(ConvArgs a)
{
    int stride = gridDim.x * blockDim.x;
    for (int seg = 0; seg < a.nseg; ++seg) {
        const float4v* src = (const float4v*)a.s[seg];
        unsigned short* dst = a.d[seg];
        int n4 = a.n4[seg];
        for (int i = blockIdx.x * blockDim.x + threadIdx.x; i < n4; i += stride) {
            float4v v = src[i];
            dst[i*4+0] = f2b(v.x); dst[i*4+1] = f2b(v.y);
            dst[i*4+2] = f2b(v.z); dst[i*4+3] = f2b(v.w);
        }
    }
}

// ---------------------------------------------------------------------------
// build LSTM concatenated weights Wcat_s = [wih_s | whh_s] (2048 x 1024) bf16
// and Xcat_s = [x | lstm_h_s] (256 x 1024) bf16
// ---------------------------------------------------------------------------
__global__ void build_lstm_cat(const float* __restrict__ wih, const float* __restrict__ whh,
                               const float* __restrict__ x, const float* __restrict__ lh,
                               unsigned short* __restrict__ Wcat, unsigned short* __restrict__ Xcat)
{
    int stride = gridDim.x * blockDim.x;
    const int W4 = 3 * 2048 * 256;   // float4 groups in Wcat
    const int X4 = 3 * 256 * 256;
    for (int g = blockIdx.x * blockDim.x + threadIdx.x; g < W4; g += stride) {
        int s = g / 524288;
        int rr = g - s * 524288;
        int r = rr >> 8;            // 0..2047
        int c = (rr & 255) * 4;     // 0..1020
        const float* src = (c < 512) ? (wih + (size_t)s * 1048576 + (size_t)r * 512 + c)
                                     : (whh + (size_t)s * 1048576 + (size_t)r * 512 + (c - 512));
        float4v v = *(const float4v*)src;
        unsigned short* dst = Wcat + (size_t)s * 2097152 + (size_t)r * 1024 + c;
        dst[0] = f2b(v.x); dst[1] = f2b(v.y); dst[2] = f2b(v.z); dst[3] = f2b(v.w);
    }
    for (int g = blockIdx.x * blockDim.x + threadIdx.x; g < X4; g += stride) {
        int s = g / 65536;
        int rr = g - s * 65536;
        int b = rr >> 8;
        int c = (rr & 255) * 4;
        const float* src = (c < 512) ? (x + (size_t)b * 512 + c)
                                     : (lh + (size_t)s * 131072 + (size_t)b * 512 + (c - 512));
        float4v v = *(const float4v*)src;
        unsigned short* dst = Xcat + (size_t)s * 262144 + (size_t)b * 1024 + c;
        dst[0] = f2b(v.x); dst[1] = f2b(v.y); dst[2] = f2b(v.z); dst[3] = f2b(v.w);
    }
}

// ---------------------------------------------------------------------------
// A^T (bf16):  ATb[n*512+k] = A[k*512+n]
// ---------------------------------------------------------------------------
__global__ void transposeA_bf16(const float* __restrict__ A, unsigned short* __restrict__ ATb)
{
    __shared__ float tile[32][33];
    int x = blockIdx.x * 32 + threadIdx.x;
    int y = blockIdx.y * 32 + threadIdx.y;
    #pragma unroll
    for (int i = 0; i < 32; i += 8)
        tile[threadIdx.y + i][threadIdx.x] = A[(size_t)(y + i) * DIM + x];
    __syncthreads();
    x = blockIdx.y * 32 + threadIdx.x;
    y = blockIdx.x * 32 + threadIdx.y;
    #pragma unroll
    for (int i = 0; i < 32; i += 8)
        ATb[(size_t)(y + i) * DIM + x] = f2b(tile[threadIdx.x][threadIdx.y + i]);
}

// ---------------------------------------------------------------------------
__device__ __forceinline__ void block_reduce2(float& s, float& q, float* sb1, float* sb2)
{
    int tid = threadIdx.x;
    #pragma unroll
    for (int off = 32; off > 0; off >>= 1) {
        s += __shfl_down(s, off);
        q += __shfl_down(q, off);
    }
    if ((tid & 63) == 0) { sb1[tid >> 6] = s; sb2[tid >> 6] = q; }
    __syncthreads();
    s = sb1[0] + sb1[1] + sb1[2] + sb1[3];
    q = sb2[0] + sb2[1] + sb2[2] + sb2[3];
    __syncthreads();
}

// LayerNorm + GELU + delta = softplus(h1.w2+b2) + Taylor coefficients
__global__ __launch_bounds__(256) void ln_gelu_delta(
    const float* __restrict__ pre, const float* __restrict__ g,
    const float* __restrict__ beta, const float* __restrict__ w2,
    const float* __restrict__ b2, float* __restrict__ delta,
    float* __restrict__ coeff)
{
    __shared__ float sb1[4], sb2[4];
    int b = blockIdx.x, tid = threadIdx.x;
    int i0 = tid, i1 = tid + 256;
    float x0 = pre[(size_t)b * DIM + i0];
    float x1 = pre[(size_t)b * DIM + i1];
    float s = x0 + x1, q = x0 * x0 + x1 * x1;
    block_reduce2(s, q, sb1, sb2);
    float mean = s * (1.f / DIM);
    float var  = q * (1.f / DIM) - mean * mean;
    float inv  = rsqrtf(var + 1e-5f);
    float y0 = (x0 - mean) * inv * g[i0] + beta[i0];
    float y1 = (x1 - mean) * inv * g[i1] + beta[i1];
    float h0 = 0.5f * y0 * (1.f + erff(y0 * 0.70710678118654752f));
    float h1 = 0.5f * y1 * (1.f + erff(y1 * 0.70710678118654752f));
    float p = h0 * w2[i0] + h1 * w2[i1];
    float dummy = 0.f;
    block_reduce2(p, dummy, sb1, sb2);
    if (tid == 0) {
        float z = p + b2[0];
        float d = (z > 20.f) ? z : log1pf(expf(z));
        delta[b] = d;
        float c = 1.f;
        coeff[b] = 1.f;
        for (int k = 1; k <= KMAX; ++k) { c *= d / (float)k; coeff[k * 256 + b] = c; }
    }
}

// ---------------------------------------------------------------------------
// Taylor accumulate.  T (256x2048 fp32) holds [A^1..A^4]^(g) applied to U_g.
// acc += sum coeff; U_{g+1} = T[:,1536:] (bf16); final: h_ssm + combb slice.
// ---------------------------------------------------------------------------
__global__ void taylor_accum(
    const float* __restrict__ T, const float* __restrict__ coeff, int g,
    const float* __restrict__ h_prev, float* __restrict__ acc,
    unsigned short* __restrict__ Ub, int final_flag,
    const float* __restrict__ delta, const float* __restrict__ Bx,
    float* __restrict__ hssm, unsigned short* __restrict__ combb)
{
    int idx = blockIdx.x * 256 + threadIdx.x;   // 0..131071
    int b = idx >> 9, i = idx & 511;
    const float* Tr = T + (size_t)b * 2048;
    int k0 = g * 4;
    float a = (g == 0 ? h_prev[idx] : acc[idx])
            + coeff[(k0 + 1) * 256 + b] * Tr[i]
            + coeff[(k0 + 2) * 256 + b] * Tr[512 + i]
            + coeff[(k0 + 3) * 256 + b] * Tr[1024 + i]
            + coeff[(k0 + 4) * 256 + b] * Tr[1536 + i];
    Ub[idx] = f2b(Tr[1536 + i]);
    if (final_flag) {
        float h = a + delta[b] * Bx[idx];
        hssm[idx] = h;
        combb[(size_t)b * 2560 + i] = f2b(h);
    } else {
        acc[idx] = a;
    }
}

// ---------------------------------------------------------------------------
// LSTM cell: gates (3,256,2048) fp32 (no bias yet) -> h_new, c_new fp32 out,
// bf16 h_new into combb cols 1024+s*512.
// ---------------------------------------------------------------------------
__global__ void lstm_cell(
    const float* __restrict__ gates, const float* __restrict__ bih,
    const float* __restrict__ bhh, const float* __restrict__ cin,
    const float* __restrict__ decays,
    float* __restrict__ hout, float* __restrict__ cout,
    unsigned short* __restrict__ combb)
{
    int idx = blockIdx.x * 256 + threadIdx.x;   // 0..393215
    int s = idx / (NB * DIM);
    int r = idx - s * (NB * DIM);
    int b = r >> 9, d = r & 511;
    const float* gr = gates + (size_t)s * 524288 + (size_t)b * 2048;
    const float* bi = bih + s * 2048;
    const float* bh = bhh + s * 2048;
    float gi = gr[d]        + bi[d]        + bh[d];
    float gf = gr[512 + d]  + bi[512 + d]  + bh[512 + d];
    float gg = gr[1024 + d] + bi[1024 + d] + bh[1024 + d];
    float go = gr[1536 + d] + bi[1536 + d] + bh[1536 + d];
    float ig = 1.f / (1.f + expf(-gi));
    float fg = 1.f / (1.f + expf(-gf));
    float g_ = tanhf(gg);
    float og = 1.f / (1.f + expf(-go));
    float c  = cin[idx];
    float craw = fg * c + ig * g_;
    float hn = og * tanhf(craw);
    float dec = decays[s];
    hout[idx] = hn;
    cout[idx] = dec * c + (1.f - dec) * craw;
    combb[(size_t)b * 2560 + 1024 + s * 512 + d] = f2b(hn);
}

// ---------------------------------------------------------------------------
// Attention: 1 query, 3 keys per (b,h).  One wave per (b,h).
// kvb: per s (256 x 1024): cols 0..511 = k, 512..1023 = v.
// ---------------------------------------------------------------------------
__global__ __launch_bounds__(64) void attn_kernel(
    const unsigned short* __restrict__ qb, const unsigned short* __restrict__ kvb,
    unsigned short* __restrict__ ctxb)
{
    int bh = blockIdx.x;
    int b = bh >> 3, h = bh & 7;
    int e = threadIdx.x;
    int col = h * 64 + e;
    float qe = b2f(qb[(size_t)b * 512 + col]);
    float p0 = qe * b2f(kvb[0 * 262144 + (size_t)b * 1024 + col]);
    float p1 = qe * b2f(kvb[1 * 262144 + (size_t)b * 1024 + col]);
    float p2 = qe * b2f(kvb[2 * 262144 + (size_t)b * 1024 + col]);
    #pragma unroll
    for (int off = 32; off > 0; off >>= 1) {
        p0 += __shfl_xor(p0, off);
        p1 += __shfl_xor(p1, off);
        p2 += __shfl_xor(p2, off);
    }
    const float scale = 0.125f;
    p0 *= scale; p1 *= scale; p2 *= scale;
    float m = fmaxf(p0, fmaxf(p1, p2));
    float w0 = expf(p0 - m), w1 = expf(p1 - m), w2 = expf(p2 - m);
    float invs = 1.f / (w0 + w1 + w2);
    float v0 = b2f(kvb[0 * 262144 + (size_t)b * 1024 + 512 + col]);
    float v1 = b2f(kvb[1 * 262144 + (size_t)b * 1024 + 512 + col]);
    float v2 = b2f(kvb[2 * 262144 + (size_t)b * 1024 + 512 + col]);
    ctxb[(size_t)b * 512 + col] = f2b((w0 * v0 + w1 * v1 + w2 * v2) * invs);
}

// ---------------------------------------------------------------------------
__global__ __launch_bounds__(256) void layernorm_k(
    const float* __restrict__ in, const float* __restrict__ g,
    const float* __restrict__ beta, float* __restrict__ outp)
{
    __shared__ float sb1[4], sb2[4];
    int b = blockIdx.x, tid = threadIdx.x;
    int i0 = tid, i1 = tid + 256;
    float x0 = in[(size_t)b * DIM + i0];
    float x1 = in[(size_t)b * DIM + i1];
    float s = x0 + x1, q = x0 * x0 + x1 * x1;
    block_reduce2(s, q, sb1, sb2);
    float mean = s * (1.f / DIM);
    float var  = q * (1.f / DIM) - mean * mean;
    float inv  = rsqrtf(var + 1e-5f);
    outp[(size_t)b * DIM + i0] = (x0 - mean) * inv * g[i0] + beta[i0];
    outp[(size_t)b * DIM + i1] = (x1 - mean) * inv * g[i1] + beta[i1];
}

// ---------------------------------------------------------------------------
extern "C" void kernel_launch(void* const* d_in, const int* in_sizes, int n_in,
                              void* d_out, int out_size, void* d_ws, size_t ws_size,
                              hipStream_t stream)
{
    const float* x        = (const float*)d_in[0];
    const float* h_prev   = (const float*)d_in[1];
    const float* lstm_h   = (const float*)d_in[2];
    const float* lstm_c   = (const float*)d_in[3];
    const float* A        = (const float*)d_in[4];
    const float* Bm       = (const float*)d_in[5];
    const float* dn_w1    = (const float*)d_in[6];
    const float* dn_b1    = (const float*)d_in[7];
    const float* dn_g     = (const float*)d_in[8];
    const float* dn_beta  = (const float*)d_in[9];
    const float* dn_w2    = (const float*)d_in[10];
    const float* dn_b2    = (const float*)d_in[11];
    const float* wih      = (const float*)d_in[12];
    const float* whh      = (const float*)d_in[13];
    const float* bih      = (const float*)d_in[14];
    const float* bhh      = (const float*)d_in[15];
    const float* decays   = (const float*)d_in[16];
    const float* ain_w    = (const float*)d_in[17];
    const float* ain_b    = (const float*)d_in[18];
    const float* aout_w   = (const float*)d_in[19];
    const float* aout_b   = (const float*)d_in[20];
    const float* proj_w   = (const float*)d_in[21];
    const float* proj_b   = (const float*)d_in[22];
    const float* proj_g   = (const float*)d_in[23];
    const float* proj_bt  = (const float*)d_in[24];

    float* out  = (float*)d_out;
    float* hssm = out + 131072;
    float* hnew = out + 262144;
    float* cnew = out + 655360;

    // ---- workspace layout ----
    unsigned short* us = (unsigned short*)d_ws;
    unsigned short* xb      = us;                 // 131072
    unsigned short* hpb     = us + 131072;        // 131072
    unsigned short* ATb     = us + 262144;        // 262144   (A^T bf16)
    unsigned short* dn_w1b  = us + 524288;        // 262144
    unsigned short* Bmb     = us + 786432;        // 262144
    unsigned short* ain_wb  = us + 1048576;       // 786432
    unsigned short* aout_wb = us + 1835008;       // 262144
    unsigned short* proj_wb = us + 2097152;       // 1310720
    unsigned short* Pw      = us + 3407872;       // 1048576 (2048 x 512) [A|A2|A3|A4]
    unsigned short* Wcat    = us + 4456448;       // 6291456
    unsigned short* Xcat    = us + 10747904;      // 786432
    unsigned short* Ub      = us + 11534336;      // 131072
    unsigned short* combb   = us + 11665408;      // 655360 (256 x 2560)
    unsigned short* kvb     = us + 12320768;      // 786432
    unsigned short* qb      = us + 13107200;      // 131072
    unsigned short* ctxb    = us + 13238272;      // 131072
    float* fbase = (float*)(us + 13369344);
    float* pre1   = fbase;                        // 131072 (reused as projout)
    float* delta  = fbase + 131072;               // 256
    float* coeff  = fbase + 131328;               // 6400
    float* Bx     = fbase + 137728;               // 131072
    float* acc    = fbase + 268800;               // 131072
    float* Tm     = fbase + 399872;               // 524288
    float* gates  = Tm;                           // 1572864 (aliases Tm; Tm dead)
    float* projout = pre1;

    // ---- 1. conversions ----
    ConvArgs ca;
    ca.s[0] = x;      ca.d[0] = xb;      ca.n4[0] = 131072/4;
    ca.s[1] = h_prev; ca.d[1] = hpb;     ca.n4[1] = 131072/4;
    ca.s[2] = A;      ca.d[2] = Pw;      ca.n4[2] = 262144/4;   // Pw block 0 = bf16(A), untransposed
    ca.s[3] = dn_w1;  ca.d[3] = dn_w1b;  ca.n4[3] = 262144/4;
    ca.s[4] = Bm;     ca.d[4] = Bmb;     ca.n4[4] = 262144/4;
    ca.s[5] = ain_w;  ca.d[5] = ain_wb;  ca.n4[5] = 786432/4;
    ca.s[6] = aout_w; ca.d[6] = aout_wb; ca.n4[6] = 262144/4;
    ca.s[7] = proj_w; ca.d[7] = proj_wb; ca.n4[7] = 1310720/4;
    ca.nseg = 8;
    convert_pairs<<<1024, 256, 0, stream>>>(ca);
    build_lstm_cat<<<2048, 256, 0, stream>>>(wih, whh, x, lstm_h, Wcat, Xcat);
    transposeA_bf16<<<dim3(16, 16), dim3(32, 8), 0, stream>>>(A, ATb);

    GemmArgs ga;
    // ---- 2. dense1 + Bx (batched) ----
    ga.d[0] = { xb, dn_w1b, dn_b1, pre1, nullptr, 256, 512, 512, 512, 512 };
    ga.d[1] = { xb, Bmb,    nullptr, Bx,  nullptr, 256, 512, 512, 512, 512 };
    gemm_mfma<<<dim3(32, 2), 256, 0, stream>>>(ga);
    ln_gelu_delta<<<256, 256, 0, stream>>>(pre1, dn_g, dn_beta, dn_w2, dn_b2, delta, coeff);

    // ---- 3. powers (UNtransposed): Pw_{p+1}[m,n] = sum_k Pw_p[m,k] * A^T[n,k]
    //         = (A^{p+1} . A)[m,n] = A^{p+2}[m,n]  ----
    for (int p = 0; p < 3; ++p) {
        ga.d[0] = { Pw + (size_t)p * 262144, ATb, nullptr, nullptr,
                    Pw + (size_t)(p + 1) * 262144, 512, 512, 512, 512, 512 };
        gemm_mfma<<<dim3(64, 1), 256, 0, stream>>>(ga);
    }

    // ---- 4. Taylor series: 6 groups x 4 powers = 24 terms
    //         T[b, p*512+i] = sum_k U[b,k] * A^{p+1}[i,k]  -- wait, W[n,k]=Pw[n',k]=A^{p+1}[n',k]
    //         => T[b,n'] = sum_k U[b,k] A^{p+1}[n',k] = (A^{p+1} u_b)[n']  (correct, row-major A^p as B^T)
    for (int g = 0; g < NGROUP; ++g) {
        ga.d[0] = { (g == 0) ? hpb : Ub, Pw, nullptr, Tm, nullptr,
                    256, 2048, 512, 512, 2048 };
        gemm_mfma<<<dim3(128, 1), 256, 0, stream>>>(ga);
        taylor_accum<<<512, 256, 0, stream>>>(Tm, coeff, g, h_prev, acc, Ub,
            (g == NGROUP - 1) ? 1 : 0, delta, Bx, hssm, combb);
    }

    // ---- 5. LSTM: 3 fused GEMMs (one launch) + cell ----
    for (int s = 0; s < 3; ++s)
        ga.d[s] = { Xcat + (size_t)s * 262144, Wcat + (size_t)s * 2097152, nullptr,
                    gates + (size_t)s * 524288, nullptr, 256, 2048, 1024, 1024, 2048 };
    gemm_mfma<<<dim3(128, 3), 256, 0, stream>>>(ga);
    lstm_cell<<<1536, 256, 0, stream>>>(gates, bih, bhh, lstm_c, decays, hnew, cnew, combb);

    // ---- 6. attention: q + kv_s (batched), softmax, out-proj ----
    ga.d[0] = { combb, ain_wb, ain_b, nullptr, qb, 256, 512, 512, 2560, 512 };
    for (int s = 0; s < 3; ++s)
        ga.d[1 + s] = { combb + 1024 + (size_t)s * 512, ain_wb + 262144, ain_b + 512,
                        nullptr, kvb + (size_t)s * 262144, 256, 1024, 512, 2560, 1024 };
    gemm_mfma<<<dim3(64, 4), 256, 0, stream>>>(ga);
    attn_kernel<<<2048, 64, 0, stream>>>(qb, kvb, ctxb);
    ga.d[0] = { ctxb, aout_wb, aout_b, nullptr, combb + 512, 256, 512, 512, 512, 2560 };
    gemm_mfma<<<dim3(32, 1), 256, 0, stream>>>(ga);

    // ---- 7. projection + final LN ----
    ga.d[0] = { combb, proj_wb, proj_b, projout, nullptr, 256, 512, 2560, 2560, 512 };
    gemm_mfma<<<dim3(32, 1), 256, 0, stream>>>(ga);
    layernorm_k<<<256, 256, 0, stream>>>(projout, proj_g, proj_bt, out);
}

// Round 4
// 273.087 us; speedup vs baseline: 2.9176x; 1.2857x over previous
//
#include <hip/hip_runtime.h>
#include <math.h>

#define DIM 512
#define NS 3
#define NB 256
#define KMAX 24   // Taylor terms (powers A^1..A^24)

using bf16x8 = __attribute__((ext_vector_type(8))) short;
using f32x4  = __attribute__((ext_vector_type(4))) float;
using float4v = __attribute__((ext_vector_type(4))) float;

// fp32 -> bf16 (RNE) and back
__device__ __forceinline__ unsigned short f2b(float f) {
    union { float f; unsigned int u; } v; v.f = f;
    unsigned int r = v.u + 0x7fffu + ((v.u >> 16) & 1u);
    return (unsigned short)(r >> 16);
}
__device__ __forceinline__ float b2f(unsigned short u) {
    union { unsigned int u; float f; } v; v.u = ((unsigned int)u) << 16;
    return v.f;
}

// ---------------------------------------------------------------------------
// Batched bf16 MFMA GEMM:  C[m,n] = sum_k X[m,k]*W[n,k] + bias[n]
// X: (M,K) bf16 ld=ldX.  W: (N,K) bf16 ld=K.  C: fp32 (Cf) or bf16 (Cb), ld=ldC.
// Optional transposed bf16 dual-write: rows >= tr_row0 go to Ct[col*512+(row-tr_row0)].
// Tile 64x64, BK=64 (two 32-halves), 256 threads (4 waves 2x2), double-buffered
// LDS, global_load_lds dwordx4 staging with 64B-contiguous 4-lane groups.
// M,N multiples of 64; K multiple of 64.
// ---------------------------------------------------------------------------
struct GemmDesc {
    const unsigned short* X;
    const unsigned short* W;
    const float* bias;
    float* Cf;
    unsigned short* Cb;
    unsigned short* Ct;
    int M, N, K, ldX, ldC, tr_row0;
};
struct GemmArgs { GemmDesc d[4]; };

__global__ __launch_bounds__(256) void gemm_mfma(GemmArgs args)
{
    GemmDesc de = args.d[blockIdx.y];
    int tn = de.N >> 6;
    int tiles = (de.M >> 6) * tn;
    int t = blockIdx.x;
    if (t >= tiles) return;
    int m0 = (t / tn) << 6;
    int n0 = (t % tn) << 6;

    // per buffer: 64 rows x 64 k-elems = 4096 bf16 = 8KB, as two 32-k halves.
    // slot (16B) within half = (row>>4)*64 + (row&15)*4 + chunk ; half offset 2048 elems.
    __shared__ unsigned short lsA[2][4096];
    __shared__ unsigned short lsB[2][4096];

    int tid = threadIdx.x;
    int w = tid >> 6;        // wave 0..3
    int l = tid & 63;        // lane

    int nkt = de.K >> 6;

    // staging: wave w, lane l -> row = w*16 + l/4, chunk = l&3 (8 elems = 16B)
    int srow = w * 16 + (l >> 2);
    int schk = l & 3;
    const unsigned short* gA = de.X + (size_t)(m0 + srow) * de.ldX + schk * 8;
    const unsigned short* gB = de.W + (size_t)(n0 + srow) * de.K  + schk * 8;
    unsigned short* lA = &lsA[0][(w * 64 + l) * 8];
    unsigned short* lB = &lsB[0][(w * 64 + l) * 8];

#define STAGE(bufi, kt)                                                          \
    do {                                                                         \
        __builtin_amdgcn_global_load_lds(                                        \
            (const __attribute__((address_space(1))) unsigned int*)(gA + (size_t)(kt) * 64), \
            (__attribute__((address_space(3))) unsigned int*)(lA + (bufi) * 4096), 16, 0, 0); \
        __builtin_amdgcn_global_load_lds(                                        \
            (const __attribute__((address_space(1))) unsigned int*)(gA + (size_t)(kt) * 64 + 32), \
            (__attribute__((address_space(3))) unsigned int*)(lA + (bufi) * 4096 + 2048), 16, 0, 0); \
        __builtin_amdgcn_global_load_lds(                                        \
            (const __attribute__((address_space(1))) unsigned int*)(gB + (size_t)(kt) * 64), \
            (__attribute__((address_space(3))) unsigned int*)(lB + (bufi) * 4096), 16, 0, 0); \
        __builtin_amdgcn_global_load_lds(                                        \
            (const __attribute__((address_space(1))) unsigned int*)(gB + (size_t)(kt) * 64 + 32), \
            (__attribute__((address_space(3))) unsigned int*)(lB + (bufi) * 4096 + 2048), 16, 0, 0); \
    } while (0)

    int mbase = (w >> 1) * 32;   // wave's 32x32 subtile
    int nbase = (w & 1) * 32;

    f32x4 acc[2][2];
    #pragma unroll
    for (int i = 0; i < 2; ++i)
        #pragma unroll
        for (int j = 0; j < 2; ++j)
            acc[i][j] = (f32x4){0.f, 0.f, 0.f, 0.f};

    int kg = l >> 4;       // 0..3  (k-chunk within 32-half)
    int fr = l & 15;       // frag row/col
    // frag elem offset within half: slot = baserow*4 + fr*4 + kg  (16B units)
    int aslot = (mbase * 4 + fr * 4 + kg) * 8;
    int bslot = (nbase * 4 + fr * 4 + kg) * 8;

    STAGE(0, 0);

    for (int kt = 0; kt < nkt; ++kt) {
        __syncthreads();                    // drains vmcnt -> buf[kt&1] ready
        if (kt + 1 < nkt) STAGE((kt + 1) & 1, kt + 1);

        const unsigned short* bufA = &lsA[kt & 1][0];
        const unsigned short* bufB = &lsB[kt & 1][0];
        #pragma unroll
        for (int h = 0; h < 2; ++h) {
            bf16x8 a0 = *(const bf16x8*)(bufA + h * 2048 + aslot);
            bf16x8 a1 = *(const bf16x8*)(bufA + h * 2048 + aslot + 512);
            bf16x8 b0 = *(const bf16x8*)(bufB + h * 2048 + bslot);
            bf16x8 b1 = *(const bf16x8*)(bufB + h * 2048 + bslot + 512);
            acc[0][0] = __builtin_amdgcn_mfma_f32_16x16x32_bf16(a0, b0, acc[0][0], 0, 0, 0);
            acc[0][1] = __builtin_amdgcn_mfma_f32_16x16x32_bf16(a0, b1, acc[0][1], 0, 0, 0);
            acc[1][0] = __builtin_amdgcn_mfma_f32_16x16x32_bf16(a1, b0, acc[1][0], 0, 0, 0);
            acc[1][1] = __builtin_amdgcn_mfma_f32_16x16x32_bf16(a1, b1, acc[1][1], 0, 0, 0);
        }
    }

    // epilogue: C/D layout col = lane&15, row = (lane>>4)*4 + reg
    #pragma unroll
    for (int mi = 0; mi < 2; ++mi) {
        #pragma unroll
        for (int ni = 0; ni < 2; ++ni) {
            int col = n0 + nbase + ni * 16 + fr;
            float bv = de.bias ? de.bias[col] : 0.f;
            #pragma unroll
            for (int r = 0; r < 4; ++r) {
                int row = m0 + mbase + mi * 16 + (l >> 4) * 4 + r;
                float v = acc[mi][ni][r] + bv;
                if (de.Cf) de.Cf[(size_t)row * de.ldC + col] = v;
                else       de.Cb[(size_t)row * de.ldC + col] = f2b(v);
                if (de.Ct && row >= de.tr_row0)
                    de.Ct[(size_t)col * 512 + (row - de.tr_row0)] = f2b(v);
            }
        }
    }
#undef STAGE
}

// ---------------------------------------------------------------------------
// multi-array fp32 -> bf16 convert (vectorized by 4)
// ---------------------------------------------------------------------------
struct ConvArgs { const float* s[8]; unsigned short* d[8]; int n4[8]; int nseg; };
__global__ void convert_pairs(ConvArgs a)
{
    int stride = gridDim.x * blockDim.x;
    for (int seg = 0; seg < a.nseg; ++seg) {
        const float4v* src = (const float4v*)a.s[seg];
        unsigned short* dst = a.d[seg];
        int n4 = a.n4[seg];
        for (int i = blockIdx.x * blockDim.x + threadIdx.x; i < n4; i += stride) {
            float4v v = src[i];
            dst[i*4+0] = f2b(v.x); dst[i*4+1] = f2b(v.y);
            dst[i*4+2] = f2b(v.z); dst[i*4+3] = f2b(v.w);
        }
    }
}

// ---------------------------------------------------------------------------
// build LSTM concatenated weights Wcat_s = [wih_s | whh_s] (2048 x 1024) bf16
// and Xcat_s = [x | lstm_h_s] (256 x 1024) bf16
// ---------------------------------------------------------------------------
__global__ void build_lstm_cat(const float* __restrict__ wih, const float* __restrict__ whh,
                               const float* __restrict__ x, const float* __restrict__ lh,
                               unsigned short* __restrict__ Wcat, unsigned short* __restrict__ Xcat)
{
    int stride = gridDim.x * blockDim.x;
    const int W4 = 3 * 2048 * 256;   // float4 groups in Wcat
    const int X4 = 3 * 256 * 256;
    for (int g = blockIdx.x * blockDim.x + threadIdx.x; g < W4; g += stride) {
        int s = g / 524288;
        int rr = g - s * 524288;
        int r = rr >> 8;            // 0..2047
        int c = (rr & 255) * 4;     // 0..1020
        const float* src = (c < 512) ? (wih + (size_t)s * 1048576 + (size_t)r * 512 + c)
                                     : (whh + (size_t)s * 1048576 + (size_t)r * 512 + (c - 512));
        float4v v = *(const float4v*)src;
        unsigned short* dst = Wcat + (size_t)s * 2097152 + (size_t)r * 1024 + c;
        dst[0] = f2b(v.x); dst[1] = f2b(v.y); dst[2] = f2b(v.z); dst[3] = f2b(v.w);
    }
    for (int g = blockIdx.x * blockDim.x + threadIdx.x; g < X4; g += stride) {
        int s = g / 65536;
        int rr = g - s * 65536;
        int b = rr >> 8;
        int c = (rr & 255) * 4;
        const float* src = (c < 512) ? (x + (size_t)b * 512 + c)
                                     : (lh + (size_t)s * 131072 + (size_t)b * 512 + (c - 512));
        float4v v = *(const float4v*)src;
        unsigned short* dst = Xcat + (size_t)s * 262144 + (size_t)b * 1024 + c;
        dst[0] = f2b(v.x); dst[1] = f2b(v.y); dst[2] = f2b(v.z); dst[3] = f2b(v.w);
    }
}

// ---------------------------------------------------------------------------
// A^T (bf16):  ATb[n*512+k] = A[k*512+n]
// ---------------------------------------------------------------------------
__global__ void transposeA_bf16(const float* __restrict__ A, unsigned short* __restrict__ ATb)
{
    __shared__ float tile[32][33];
    int x = blockIdx.x * 32 + threadIdx.x;
    int y = blockIdx.y * 32 + threadIdx.y;
    #pragma unroll
    for (int i = 0; i < 32; i += 8)
        tile[threadIdx.y + i][threadIdx.x] = A[(size_t)(y + i) * DIM + x];
    __syncthreads();
    x = blockIdx.y * 32 + threadIdx.x;
    y = blockIdx.x * 32 + threadIdx.y;
    #pragma unroll
    for (int i = 0; i < 32; i += 8)
        ATb[(size_t)(y + i) * DIM + x] = f2b(tile[threadIdx.x][threadIdx.y + i]);
}

// ---------------------------------------------------------------------------
__device__ __forceinline__ void block_reduce2(float& s, float& q, float* sb1, float* sb2)
{
    int tid = threadIdx.x;
    #pragma unroll
    for (int off = 32; off > 0; off >>= 1) {
        s += __shfl_down(s, off);
        q += __shfl_down(q, off);
    }
    if ((tid & 63) == 0) { sb1[tid >> 6] = s; sb2[tid >> 6] = q; }
    __syncthreads();
    s = sb1[0] + sb1[1] + sb1[2] + sb1[3];
    q = sb2[0] + sb2[1] + sb2[2] + sb2[3];
    __syncthreads();
}

// LayerNorm + GELU + delta = softplus(h1.w2+b2) + Taylor coefficients
__global__ __launch_bounds__(256) void ln_gelu_delta(
    const float* __restrict__ pre, const float* __restrict__ g,
    const float* __restrict__ beta, const float* __restrict__ w2,
    const float* __restrict__ b2, float* __restrict__ delta,
    float* __restrict__ coeff)
{
    __shared__ float sb1[4], sb2[4];
    int b = blockIdx.x, tid = threadIdx.x;
    int i0 = tid, i1 = tid + 256;
    float x0 = pre[(size_t)b * DIM + i0];
    float x1 = pre[(size_t)b * DIM + i1];
    float s = x0 + x1, q = x0 * x0 + x1 * x1;
    block_reduce2(s, q, sb1, sb2);
    float mean = s * (1.f / DIM);
    float var  = q * (1.f / DIM) - mean * mean;
    float inv  = rsqrtf(var + 1e-5f);
    float y0 = (x0 - mean) * inv * g[i0] + beta[i0];
    float y1 = (x1 - mean) * inv * g[i1] + beta[i1];
    float h0 = 0.5f * y0 * (1.f + erff(y0 * 0.70710678118654752f));
    float h1 = 0.5f * y1 * (1.f + erff(y1 * 0.70710678118654752f));
    float p = h0 * w2[i0] + h1 * w2[i1];
    float dummy = 0.f;
    block_reduce2(p, dummy, sb1, sb2);
    if (tid == 0) {
        float z = p + b2[0];
        float d = (z > 20.f) ? z : log1pf(expf(z));
        delta[b] = d;
        float c = 1.f;
        coeff[b] = 1.f;
        for (int k = 1; k <= KMAX; ++k) { c *= d / (float)k; coeff[k * 256 + b] = c; }
    }
}

// ---------------------------------------------------------------------------
// Taylor final: h_ssm[b,i] = h_prev + sum_{k=1..24} coeff[k,b]*T[b,(k-1)*512+i]
//               + delta[b]*Bx ;  also bf16 into combb cols 0..511.
// T: (256 x 12288) fp32.
// ---------------------------------------------------------------------------
__global__ void taylor_accum(
    const float* __restrict__ T, const float* __restrict__ coeff,
    const float* __restrict__ h_prev, const float* __restrict__ delta,
    const float* __restrict__ Bx, float* __restrict__ hssm,
    unsigned short* __restrict__ combb)
{
    int idx = blockIdx.x * 256 + threadIdx.x;   // 0..131071
    int b = idx >> 9, i = idx & 511;
    const float* Tr = T + (size_t)b * (KMAX * DIM) + i;
    float a = h_prev[idx];
    #pragma unroll
    for (int k = 1; k <= KMAX; ++k)
        a += coeff[k * 256 + b] * Tr[(size_t)(k - 1) * DIM];
    float h = a + delta[b] * Bx[idx];
    hssm[idx] = h;
    combb[(size_t)b * 2560 + i] = f2b(h);
}

// ---------------------------------------------------------------------------
// LSTM cell: gates (3,256,2048) fp32 (no bias yet) -> h_new, c_new fp32 out,
// bf16 h_new into combb cols 1024+s*512.
// ---------------------------------------------------------------------------
__global__ void lstm_cell(
    const float* __restrict__ gates, const float* __restrict__ bih,
    const float* __restrict__ bhh, const float* __restrict__ cin,
    const float* __restrict__ decays,
    float* __restrict__ hout, float* __restrict__ cout,
    unsigned short* __restrict__ combb)
{
    int idx = blockIdx.x * 256 + threadIdx.x;   // 0..393215
    int s = idx / (NB * DIM);
    int r = idx - s * (NB * DIM);
    int b = r >> 9, d = r & 511;
    const float* gr = gates + (size_t)s * 524288 + (size_t)b * 2048;
    const float* bi = bih + s * 2048;
    const float* bh = bhh + s * 2048;
    float gi = gr[d]        + bi[d]        + bh[d];
    float gf = gr[512 + d]  + bi[512 + d]  + bh[512 + d];
    float gg = gr[1024 + d] + bi[1024 + d] + bh[1024 + d];
    float go = gr[1536 + d] + bi[1536 + d] + bh[1536 + d];
    float ig = 1.f / (1.f + expf(-gi));
    float fg = 1.f / (1.f + expf(-gf));
    float g_ = tanhf(gg);
    float og = 1.f / (1.f + expf(-go));
    float c  = cin[idx];
    float craw = fg * c + ig * g_;
    float hn = og * tanhf(craw);
    float dec = decays[s];
    hout[idx] = hn;
    cout[idx] = dec * c + (1.f - dec) * craw;
    combb[(size_t)b * 2560 + 1024 + s * 512 + d] = f2b(hn);
}

// ---------------------------------------------------------------------------
// Attention: 1 query, 3 keys per (b,h).  One wave per (b,h).
// kvb: per s (256 x 1024): cols 0..511 = k, 512..1023 = v.
// ---------------------------------------------------------------------------
__global__ __launch_bounds__(64) void attn_kernel(
    const unsigned short* __restrict__ qb, const unsigned short* __restrict__ kvb,
    unsigned short* __restrict__ ctxb)
{
    int bh = blockIdx.x;
    int b = bh >> 3, h = bh & 7;
    int e = threadIdx.x;
    int col = h * 64 + e;
    float qe = b2f(qb[(size_t)b * 512 + col]);
    float p0 = qe * b2f(kvb[0 * 262144 + (size_t)b * 1024 + col]);
    float p1 = qe * b2f(kvb[1 * 262144 + (size_t)b * 1024 + col]);
    float p2 = qe * b2f(kvb[2 * 262144 + (size_t)b * 1024 + col]);
    #pragma unroll
    for (int off = 32; off > 0; off >>= 1) {
        p0 += __shfl_xor(p0, off);
        p1 += __shfl_xor(p1, off);
        p2 += __shfl_xor(p2, off);
    }
    const float scale = 0.125f;
    p0 *= scale; p1 *= scale; p2 *= scale;
    float m = fmaxf(p0, fmaxf(p1, p2));
    float w0 = expf(p0 - m), w1 = expf(p1 - m), w2 = expf(p2 - m);
    float invs = 1.f / (w0 + w1 + w2);
    float v0 = b2f(kvb[0 * 262144 + (size_t)b * 1024 + 512 + col]);
    float v1 = b2f(kvb[1 * 262144 + (size_t)b * 1024 + 512 + col]);
    float v2 = b2f(kvb[2 * 262144 + (size_t)b * 1024 + 512 + col]);
    ctxb[(size_t)b * 512 + col] = f2b((w0 * v0 + w1 * v1 + w2 * v2) * invs);
}

// ---------------------------------------------------------------------------
__global__ __launch_bounds__(256) void layernorm_k(
    const float* __restrict__ in, const float* __restrict__ g,
    const float* __restrict__ beta, float* __restrict__ outp)
{
    __shared__ float sb1[4], sb2[4];
    int b = blockIdx.x, tid = threadIdx.x;
    int i0 = tid, i1 = tid + 256;
    float x0 = in[(size_t)b * DIM + i0];
    float x1 = in[(size_t)b * DIM + i1];
    float s = x0 + x1, q = x0 * x0 + x1 * x1;
    block_reduce2(s, q, sb1, sb2);
    float mean = s * (1.f / DIM);
    float var  = q * (1.f / DIM) - mean * mean;
    float inv  = rsqrtf(var + 1e-5f);
    outp[(size_t)b * DIM + i0] = (x0 - mean) * inv * g[i0] + beta[i0];
    outp[(size_t)b * DIM + i1] = (x1 - mean) * inv * g[i1] + beta[i1];
}

// ---------------------------------------------------------------------------
extern "C" void kernel_launch(void* const* d_in, const int* in_sizes, int n_in,
                              void* d_out, int out_size, void* d_ws, size_t ws_size,
                              hipStream_t stream)
{
    const float* x        = (const float*)d_in[0];
    const float* h_prev   = (const float*)d_in[1];
    const float* lstm_h   = (const float*)d_in[2];
    const float* lstm_c   = (const float*)d_in[3];
    const float* A        = (const float*)d_in[4];
    const float* Bm       = (const float*)d_in[5];
    const float* dn_w1    = (const float*)d_in[6];
    const float* dn_b1    = (const float*)d_in[7];
    const float* dn_g     = (const float*)d_in[8];
    const float* dn_beta  = (const float*)d_in[9];
    const float* dn_w2    = (const float*)d_in[10];
    const float* dn_b2    = (const float*)d_in[11];
    const float* wih      = (const float*)d_in[12];
    const float* whh      = (const float*)d_in[13];
    const float* bih      = (const float*)d_in[14];
    const float* bhh      = (const float*)d_in[15];
    const float* decays   = (const float*)d_in[16];
    const float* ain_w    = (const float*)d_in[17];
    const float* ain_b    = (const float*)d_in[18];
    const float* aout_w   = (const float*)d_in[19];
    const float* aout_b   = (const float*)d_in[20];
    const float* proj_w   = (const float*)d_in[21];
    const float* proj_b   = (const float*)d_in[22];
    const float* proj_g   = (const float*)d_in[23];
    const float* proj_bt  = (const float*)d_in[24];

    float* out  = (float*)d_out;
    float* hssm = out + 131072;
    float* hnew = out + 262144;
    float* cnew = out + 655360;

    // ---- workspace layout (bf16 section) ----
    unsigned short* us = (unsigned short*)d_ws;
    unsigned short* xb      = us;                 // 131072
    unsigned short* hpb     = us + 131072;        // 131072
    unsigned short* ATb     = us + 262144;        // 262144   (A^T bf16 = Q1)
    unsigned short* dn_w1b  = us + 524288;        // 262144
    unsigned short* Bmb     = us + 786432;        // 262144
    unsigned short* ain_wb  = us + 1048576;       // 786432
    unsigned short* aout_wb = us + 1835008;       // 262144
    unsigned short* proj_wb = us + 2097152;       // 1310720
    unsigned short* Pw      = us + 3407872;       // 24*262144 = 6291456  [A^1..A^24]
    unsigned short* Qa      = us + 9699328;       // 262144
    unsigned short* Qb      = us + 9961472;       // 262144
    unsigned short* Wcat    = us + 10223616;      // 6291456
    unsigned short* Xcat    = us + 16515072;      // 786432
    unsigned short* combb   = us + 17301504;      // 655360 (256 x 2560)
    unsigned short* kvb     = us + 17956864;      // 786432
    unsigned short* qb      = us + 18743296;      // 131072
    unsigned short* ctxb    = us + 18874368;      // 131072
    // ---- fp32 section ----
    float* fbase = (float*)(us + 19005440);
    float* pre1   = fbase;                        // 131072 (reused as projout)
    float* delta  = fbase + 131072;               // 256
    float* coeff  = fbase + 131328;               // 25*256 = 6400
    float* Bx     = fbase + 137728;               // 131072
    float* Tm     = fbase + 268800;               // 256*12288 = 3145728
    float* gates  = Tm;                           // alias: 3*256*2048 = 1572864 <= Tm
    float* projout = pre1;

    // ---- 1. conversions (independent prep) ----
    ConvArgs ca;
    ca.s[0] = x;      ca.d[0] = xb;      ca.n4[0] = 131072/4;
    ca.s[1] = h_prev; ca.d[1] = hpb;     ca.n4[1] = 131072/4;
    ca.s[2] = A;      ca.d[2] = Pw;      ca.n4[2] = 262144/4;   // Pw block 0 = bf16(A)
    ca.s[3] = dn_w1;  ca.d[3] = dn_w1b;  ca.n4[3] = 262144/4;
    ca.s[4] = Bm;     ca.d[4] = Bmb;     ca.n4[4] = 262144/4;
    ca.s[5] = ain_w;  ca.d[5] = ain_wb;  ca.n4[5] = 786432/4;
    ca.s[6] = aout_w; ca.d[6] = aout_wb; ca.n4[6] = 262144/4;
    ca.s[7] = proj_w; ca.d[7] = proj_wb; ca.n4[7] = 1310720/4;
    ca.nseg = 8;
    convert_pairs<<<1024, 256, 0, stream>>>(ca);
    build_lstm_cat<<<2048, 256, 0, stream>>>(wih, whh, x, lstm_h, Wcat, Xcat);
    transposeA_bf16<<<dim3(16, 16), dim3(32, 8), 0, stream>>>(A, ATb);

    GemmArgs ga;
    // ---- 2. dense1 + Bx (batched) ----
    ga.d[0] = { xb, dn_w1b, dn_b1, pre1, nullptr, nullptr, 256, 512, 512, 512, 512, 0 };
    ga.d[1] = { xb, Bmb,    nullptr, Bx,  nullptr, nullptr, 256, 512, 512, 512, 512, 0 };
    gemm_mfma<<<dim3(32, 2), 256, 0, stream>>>(ga);
    ln_gelu_delta<<<256, 256, 0, stream>>>(pre1, dn_g, dn_beta, dn_w2, dn_b2, delta, coeff);

    // ---- 3. power chain with transposed dual-writes ----
    // G1: A^2 = A . (A^T)^T ; also Q2 = (A^2)^T
    ga.d[0] = { Pw, ATb, nullptr, nullptr, Pw + 1*262144, Qa, 512, 512, 512, 512, 512, 0 };
    gemm_mfma<<<dim3(64, 1), 256, 0, stream>>>(ga);
    // G2: [A^3;A^4] = [A;A^2] . A^2 ; Q4 from rows 512..1023
    ga.d[0] = { Pw, Qa, nullptr, nullptr, Pw + 2*262144, Qb, 1024, 512, 512, 512, 512, 512 };
    gemm_mfma<<<dim3(128, 1), 256, 0, stream>>>(ga);
    // G3: [A^5..A^8] = [A^1..A^4] . A^4 ; Q8 from rows 1536..2047
    ga.d[0] = { Pw, Qb, nullptr, nullptr, Pw + 4*262144, Qa, 2048, 512, 512, 512, 512, 1536 };
    gemm_mfma<<<dim3(256, 1), 256, 0, stream>>>(ga);
    // G4: [A^9..A^16] = [A^1..A^8] . A^8 ; Q16 from rows 3584..4095
    ga.d[0] = { Pw, Qa, nullptr, nullptr, Pw + 8*262144, Qb, 4096, 512, 512, 512, 512, 3584 };
    gemm_mfma<<<dim3(512, 1), 256, 0, stream>>>(ga);
    // G5: [A^17..A^24] = [A^1..A^8] . A^16
    ga.d[0] = { Pw, Qb, nullptr, nullptr, Pw + 16*262144, nullptr, 4096, 512, 512, 512, 512, 0 };
    gemm_mfma<<<dim3(512, 1), 256, 0, stream>>>(ga);

    // ---- 4. single Taylor GEMM: T[b, (k-1)*512+i] = (A^k h_prev_b)[i] ----
    ga.d[0] = { hpb, Pw, nullptr, Tm, nullptr, nullptr, 256, KMAX*512, 512, 512, KMAX*512, 0 };
    gemm_mfma<<<dim3(768, 1), 256, 0, stream>>>(ga);
    taylor_accum<<<512, 256, 0, stream>>>(Tm, coeff, h_prev, delta, Bx, hssm, combb);

    // ---- 5. LSTM: 3 fused GEMMs (one launch) + cell (gates alias Tm; Tm dead) ----
    for (int s = 0; s < 3; ++s)
        ga.d[s] = { Xcat + (size_t)s * 262144, Wcat + (size_t)s * 2097152, nullptr,
                    gates + (size_t)s * 524288, nullptr, nullptr, 256, 2048, 1024, 1024, 2048, 0 };
    gemm_mfma<<<dim3(128, 3), 256, 0, stream>>>(ga);
    lstm_cell<<<1536, 256, 0, stream>>>(gates, bih, bhh, lstm_c, decays, hnew, cnew, combb);

    // ---- 6. attention: q + kv_s (batched), softmax, out-proj ----
    ga.d[0] = { combb, ain_wb, ain_b, nullptr, qb, nullptr, 256, 512, 512, 2560, 512, 0 };
    for (int s = 0; s < 3; ++s)
        ga.d[1 + s] = { combb + 1024 + (size_t)s * 512, ain_wb + 262144, ain_b + 512,
                        nullptr, kvb + (size_t)s * 262144, nullptr, 256, 1024, 512, 2560, 1024, 0 };
    gemm_mfma<<<dim3(64, 4), 256, 0, stream>>>(ga);
    attn_kernel<<<2048, 64, 0, stream>>>(qb, kvb, ctxb);
    ga.d[0] = { ctxb, aout_wb, aout_b, nullptr, combb + 512, nullptr, 256, 512, 512, 512, 2560, 0 };
    gemm_mfma<<<dim3(32, 1), 256, 0, stream>>>(ga);

    // ---- 7. projection + final LN ----
    ga.d[0] = { combb, proj_wb, proj_b, projout, nullptr, nullptr, 256, 512, 2560, 2560, 512, 0 };
    gemm_mfma<<<dim3(32, 1), 256, 0, stream>>>(ga);
    layernorm_k<<<256, 256, 0, stream>>>(projout, proj_g, proj_bt, out);
}